// Round 3
// baseline (427.720 us; speedup 1.0000x reference)
//
#include <hip/hip_runtime.h>
#include <hip/hip_bf16.h>
#include <math.h>

// Problem constants
#define SEQ   128
#define BSZ   64
#define NH    256
#define NT    50000
#define NSAMP 32
#define SB    8192      // SEQ*BSZ
#define TEMPC 65.0f

__device__ __forceinline__ float rlf(float v, int lane) {
  return __uint_as_float(__builtin_amdgcn_readlane(__float_as_uint(v), lane));
}

// tanh(x) = 1 - 2/(exp(2x)+1); v_exp + v_rcp, ~1ulp, saturates correctly at +/-1
__device__ __forceinline__ float tanh_fast(float x) {
  float e = __expf(2.0f * x);
  return 1.0f - 2.0f * __builtin_amdgcn_rcpf(e + 1.0f);
}

// ---------------------------------------------------------------------------
// K0: transpose W_ih -> Wt (Wt[k*256+j] = W_ih[j*256+k]); zero the loss accum.
// ---------------------------------------------------------------------------
__global__ void k_prep(const float* __restrict__ W_ih, float* __restrict__ Wt,
                       float* __restrict__ out) {
  const int k = blockIdx.x, j = threadIdx.x;
  Wt[k * 256 + j] = W_ih[j * 256 + k];
  if (k == 0 && j == 0) out[0] = 0.0f;
}

// ---------------------------------------------------------------------------
// K1: proj[v,j] = sum_k emb[v,k] * W_ih[j,k] + b_ih[j]   (M x 256 @ 256 x 256)
// Block: 512 thr = 8 waves; block tile = 64 rows x 256 cols; wave w -> cols
// [32w,32w+32); lane l -> row l. A-tile in LDS with stride 257 (conflict-free
// per-lane row reads: bank = (l+kk)%32). W^T read at wave-uniform addresses.
// ---------------------------------------------------------------------------
__global__ __launch_bounds__(512, 4) void k_proj(const float* __restrict__ A,
    const float* __restrict__ Wt, const float* __restrict__ bias,
    float* __restrict__ out, int M) {
  __shared__ float As[64 * 257];
  const int t = threadIdx.x;
  const int l = t & 63;
  const int w = t >> 6;
  const int r0 = blockIdx.x * 64;

  // stage A tile: 64 rows x 256 cols (float4 loads, scalar LDS stores)
#pragma unroll
  for (int s = 0; s < 8; ++s) {
    int lin = t + s * 512;               // 0..4095
    int row = lin >> 6, kq = lin & 63;
    float4 v = make_float4(0.f, 0.f, 0.f, 0.f);
    if (r0 + row < M) v = ((const float4*)A)[(size_t)(r0 + row) * 64 + kq];
    float* d = &As[row * 257 + kq * 4];
    d[0] = v.x; d[1] = v.y; d[2] = v.z; d[3] = v.w;
  }
  __syncthreads();

  const int c0 = w * 32;
  const float* wbase = Wt + __builtin_amdgcn_readfirstlane(c0);
  float acc[32];
#pragma unroll
  for (int c = 0; c < 32; ++c) acc[c] = 0.f;

#pragma unroll 2
  for (int kk = 0; kk < 256; ++kk) {
    float a = As[l * 257 + kk];
    const float4* wp = (const float4*)(wbase + (kk << 8));
#pragma unroll
    for (int c4 = 0; c4 < 8; ++c4) {
      float4 wv = wp[c4];
      acc[4 * c4 + 0] = fmaf(a, wv.x, acc[4 * c4 + 0]);
      acc[4 * c4 + 1] = fmaf(a, wv.y, acc[4 * c4 + 1]);
      acc[4 * c4 + 2] = fmaf(a, wv.z, acc[4 * c4 + 2]);
      acc[4 * c4 + 3] = fmaf(a, wv.w, acc[4 * c4 + 3]);
    }
  }
  __syncthreads();

  // transpose through LDS for coalesced stores
#pragma unroll
  for (int c = 0; c < 32; ++c) As[l * 257 + c0 + c] = acc[c];
  __syncthreads();
#pragma unroll
  for (int s = 0; s < 32; ++s) {
    int lin = t + s * 512;               // 0..16383
    int row = lin >> 8, col = lin & 255;
    if (r0 + row < M)
      out[(size_t)(r0 + row) * 256 + col] = As[row * 257 + col] + bias[col];
  }
}

// ---------------------------------------------------------------------------
// K2: RNN scan, one block per batch row b. 512 thr = 8 waves.
// Wave w owns k-slice [32w, 32w+32); lane l owns output cols
// {l, l+64, l+128, l+192} (4 x 32 = 128 W_hh values in registers).
// Per step: ONE h-vector LDS read per lane + 32 readlane broadcasts reused
// across 4 FMAs each (32 readlane + 128 fma). 8 k-slice partials per column
// combined through LDS (stride-256 reads, bank = j%32, conflict-free).
// Also writes, per step t:
//   hU[t*64+b] = h_t @ W_hh^T + b_hh   (reused by K3 -- free here)
//   ro[t+1]    = h_{t+1}
//   x0[t*64+b] = 65*(bias[data_t] - ||h_t - h_{t+1}||^2)
// and new_hidden into d_out[1..] at the last step.
// ---------------------------------------------------------------------------
__global__ __launch_bounds__(512, 2) void k_scan(const float* __restrict__ proj,
    const int* __restrict__ data, const float* __restrict__ W_hh,
    const float* __restrict__ b_hh, const float* __restrict__ bias_vec,
    const float* __restrict__ hidden, float* __restrict__ ro,
    float* __restrict__ hU, float* __restrict__ x0, float* __restrict__ out) {
  __shared__ float hlds[256];
  __shared__ float part[8][256];
  __shared__ float wsum[4];
  __shared__ int   ldata[128];
  __shared__ float lbias[128];
  const int t = threadIdx.x, b = blockIdx.x;
  const int j = t & 255, l = t & 63, w = t >> 6;
  const int w32 = w * 32;

  // W_hh slice: wreg[m*32+i] = W_hh[l + 64m][w32 + i]
  float wreg[128];
#pragma unroll
  for (int m = 0; m < 4; ++m) {
    const float4* ws4 = (const float4*)(W_hh + (size_t)(l + 64 * m) * 256 + w32);
#pragma unroll
    for (int i4 = 0; i4 < 8; ++i4) {
      float4 v = ws4[i4];
      wreg[m * 32 + 4 * i4 + 0] = v.x; wreg[m * 32 + 4 * i4 + 1] = v.y;
      wreg[m * 32 + 4 * i4 + 2] = v.z; wreg[m * 32 + 4 * i4 + 3] = v.w;
    }
  }
  if (t < 128) {
    int tok = data[t * 64 + b];
    ldata[t] = tok;
    lbias[t] = bias_vec[tok];
  }
  if (t < 256) {
    float h0 = hidden[b * 256 + j];
    hlds[j] = h0;
    ro[b * 256 + j] = h0;              // ro[0] = hidden
  }
  __syncthreads();
  float bhh = (t < 256) ? b_hh[j] : 0.f;
  float xv  = (t < 256) ? proj[(size_t)ldata[0] * 256 + j] : 0.f;

  for (int st = 0; st < 128; ++st) {
    float hv = hlds[w32 + (l & 31)];     // lane i<32 holds h[w32+i] (2-way bcast)
    // prefetch next step's x row while the dot runs
    float xvn = 0.f;
    if (t < 256 && st < 127) xvn = proj[(size_t)ldata[st + 1] * 256 + j];

    float a0 = 0.f, a1 = 0.f, a2 = 0.f, a3 = 0.f;
#pragma unroll
    for (int i = 0; i < 32; ++i) {
      float h = rlf(hv, i);
      a0 = fmaf(h, wreg[i],      a0);
      a1 = fmaf(h, wreg[32 + i], a1);
      a2 = fmaf(h, wreg[64 + i], a2);
      a3 = fmaf(h, wreg[96 + i], a3);
    }
    part[w][l]       = a0;
    part[w][l + 64]  = a1;
    part[w][l + 128] = a2;
    part[w][l + 192] = a3;
    __syncthreads();

    if (t < 256) {
      float hold = hlds[j];
      float hu = ((part[0][j] + part[1][j]) + (part[2][j] + part[3][j]))
               + ((part[4][j] + part[5][j]) + (part[6][j] + part[7][j])) + bhh;
      float pre  = hu + xv;
      float hn   = tanhf(pre);
      float df   = hold - hn;
      float dsq  = df * df;
      hlds[j] = hn;
      int p = st * 64 + b;
      hU[(size_t)p * 256 + j] = hu;
      ro[((size_t)st + 1) * 16384 + b * 256 + j] = hn;
      if (st == 127) out[1 + b * 256 + j] = hn;     // new_hidden
#pragma unroll
      for (int m = 1; m < 64; m <<= 1) dsq += __shfl_xor(dsq, m);
      if (l == 0) wsum[w] = dsq;
    }
    __syncthreads();
    if (t == 0) {
      float tot = wsum[0] + wsum[1] + wsum[2] + wsum[3];
      x0[st * 64 + b] = TEMPC * (lbias[st] - tot);
    }
    xv = xvn;
  }
}

// ---------------------------------------------------------------------------
// K3: negatives + per-column logsumexp. One wave per column p (4 waves/block).
// Lane q-strided j = l + 64q. Sample tokens+biases prefetched into lanes<32,
// broadcast via readlane. Logit n stays in lane n's register; wave-wide LSE.
// Depth-1 software pipeline: iteration n issues n+1's 4 proj loads BEFORE
// n's tanh/reduce, hiding L2/L3 latency under ~50 cy of compute per step.
// ---------------------------------------------------------------------------
__global__ __launch_bounds__(256, 4) void k_loss(const float* __restrict__ ro,
    const float* __restrict__ hU, const float* __restrict__ proj,
    const int* __restrict__ samples, const float* __restrict__ bias_vec,
    const float* __restrict__ x0, float* __restrict__ out) {
  const int t = threadIdx.x, l = t & 63, w = t >> 6;
  const int p = blockIdx.x * 4 + w;
  float hp[4], hu[4];
#pragma unroll
  for (int q = 0; q < 4; ++q) {
    hp[q] = ro[(size_t)p * 256 + 64 * q + l];
    hu[q] = hU[(size_t)p * 256 + 64 * q + l];
  }
  float x0v = x0[p];
  int   stok  = (l < 32) ? samples[(size_t)l * SB + p] : 0;
  float sbias = (l < 32) ? bias_vec[stok] : 0.f;

  // prime the pipeline with n=0's proj row
  {
  }
  int tok0 = __builtin_amdgcn_readlane(stok, 0);
  const float* pc = proj + (size_t)tok0 * 256;
  float c0 = pc[l], c1 = pc[64 + l], c2 = pc[128 + l], c3 = pc[192 + l];

  float lg = 0.f;                         // lane n (<32) will hold logit n
#pragma unroll 2
  for (int n = 0; n < 32; ++n) {
    float p0 = 0.f, p1 = 0.f, p2 = 0.f, p3 = 0.f;
    if (n < 31) {                         // issue next row's loads first
      int tn = __builtin_amdgcn_readlane(stok, n + 1);
      const float* pn = proj + (size_t)tn * 256;
      p0 = pn[l]; p1 = pn[64 + l]; p2 = pn[128 + l]; p3 = pn[192 + l];
    }
    float o0 = tanh_fast(c0 + hu[0]);
    float o1 = tanh_fast(c1 + hu[1]);
    float o2 = tanh_fast(c2 + hu[2]);
    float o3 = tanh_fast(c3 + hu[3]);
    float d0 = hp[0] - o0, d1 = hp[1] - o1, d2 = hp[2] - o2, d3 = hp[3] - o3;
    float s = d0 * d0;
    s = fmaf(d1, d1, s);
    s = fmaf(d2, d2, s);
    s = fmaf(d3, d3, s);
#pragma unroll
    for (int m = 1; m < 64; m <<= 1) s += __shfl_xor(s, m);
    float bn = rlf(sbias, n);
    float logit = TEMPC * (bn - s);
    if (l == n) lg = logit;
    c0 = p0; c1 = p1; c2 = p2; c3 = p3;
  }

  float v = (l < 32) ? lg : ((l == 32) ? x0v : -INFINITY);
  float mx = v;
#pragma unroll
  for (int m = 1; m < 64; m <<= 1) mx = fmaxf(mx, __shfl_xor(mx, m));
  float e = (l < 33) ? __expf(v - mx) : 0.f;
#pragma unroll
  for (int m = 1; m < 64; m <<= 1) e += __shfl_xor(e, m);
  float lse = mx + __logf(e);

  __shared__ float bl[4];
  if (l == 0) bl[w] = lse - x0v;
  __syncthreads();
  if (t == 0) atomicAdd(out, (bl[0] + bl[1] + bl[2] + bl[3]) * (1.0f / 8192.0f));
}

// ---------------------------------------------------------------------------
// K4: loss += BIAS_REG * sum(bias_vec^2)   (50000 = 12500 float4 exactly)
// ---------------------------------------------------------------------------
__global__ __launch_bounds__(256) void k_bias2(const float* __restrict__ bv,
                                               float* __restrict__ out) {
  const int t = threadIdx.x, l = t & 63, w = t >> 6;
  int idx = blockIdx.x * 256 + t;
  float s = 0.f;
  for (int i = idx; i < 12500; i += 32 * 256) {
    float4 v = ((const float4*)bv)[i];
    s += v.x * v.x + v.y * v.y + v.z * v.z + v.w * v.w;
  }
#pragma unroll
  for (int m = 1; m < 64; m <<= 1) s += __shfl_xor(s, m);
  __shared__ float bl[4];
  if (l == 0) bl[w] = s;
  __syncthreads();
  if (t == 0) atomicAdd(out, bl[0] + bl[1] + bl[2] + bl[3]);
}

// ---------------------------------------------------------------------------
extern "C" void kernel_launch(void* const* d_in, const int* in_sizes, int n_in,
                              void* d_out, int out_size, void* d_ws, size_t ws_size,
                              hipStream_t stream) {
  const int*   data     = (const int*)  d_in[0];
  const float* hidden   = (const float*)d_in[1];
  const int*   samples  = (const int*)  d_in[2];
  const float* emb      = (const float*)d_in[3];
  const float* W_ih     = (const float*)d_in[4];
  const float* b_ih     = (const float*)d_in[5];
  const float* W_hh     = (const float*)d_in[6];
  const float* b_hh     = (const float*)d_in[7];
  const float* bias_vec = (const float*)d_in[8];
  float* out = (float*)d_out;
  float* ws  = (float*)d_ws;

  // workspace layout (floats): total ~17.1M floats = 68.3 MB
  float* proj = ws;                       // 50000*256 = 12,800,000
  float* Wt   = proj + 12800000;          // 256*256   = 65,536
  float* ro   = Wt + 65536;               // 129*64*256 = 2,113,536
  float* hU   = ro + 2113536;             // 8192*256  = 2,097,152
  float* x0v  = hU + 2097152;             // 8,192

  k_prep <<<256, 256, 0, stream>>>(W_ih, Wt, out);
  k_proj <<<782, 512, 0, stream>>>(emb, Wt, b_ih, proj, NT);
  k_scan <<<64, 512, 0, stream>>>(proj, data, W_hh, b_hh, bias_vec, hidden,
                                  ro, hU, x0v, out);
  k_loss <<<2048, 256, 0, stream>>>(ro, hU, proj, samples, bias_vec, x0v, out);
  k_bias2<<<32, 256, 0, stream>>>(bias_vec, out);
}

// Round 7
// 355.727 us; speedup vs baseline: 1.2024x; 1.2024x over previous
//
#include <hip/hip_runtime.h>
#include <hip/hip_bf16.h>
#include <math.h>

// Problem constants
#define SEQ   128
#define BSZ   64
#define NH    256
#define NT    50000
#define NSAMP 32
#define SB    8192      // SEQ*BSZ
#define TEMPC 65.0f

typedef float f32x2 __attribute__((ext_vector_type(2)));

__device__ __forceinline__ float rlf(float v, int lane) {
  return __uint_as_float(__builtin_amdgcn_readlane(__float_as_uint(v), lane));
}

// tanh(x) = 1 - 2/(exp(2x)+1); v_exp + v_rcp, ~1ulp, saturates correctly at +/-1
__device__ __forceinline__ float tanh_fast(float x) {
  float e = __expf(2.0f * x);
  return 1.0f - 2.0f * __builtin_amdgcn_rcpf(e + 1.0f);
}

// ---------------------------------------------------------------------------
// K0: transpose W_ih -> Wt (Wt[k*256+j] = W_ih[j*256+k]).
// ---------------------------------------------------------------------------
__global__ void k_prep(const float* __restrict__ W_ih, float* __restrict__ Wt) {
  const int k = blockIdx.x, j = threadIdx.x;
  Wt[k * 256 + j] = W_ih[j * 256 + k];
}

// ---------------------------------------------------------------------------
// K1: proj[v,j] = sum_k emb[v,k] * W_ih[j,k] + b_ih[j]   (M x 256 @ 256 x 256)
// Block: 512 thr = 8 waves; block tile = 64 rows x 256 cols; wave w -> cols
// [32w,32w+32); lane l -> row l. A-tile in LDS with stride 257 (conflict-free
// per-lane row reads: bank = (l+kk)%32). W^T read at wave-uniform addresses.
// Accumulators packed as f32x2 (v_pk_fma_f32 hedge; identical fp32 results).
// ---------------------------------------------------------------------------
__global__ __launch_bounds__(512, 4) void k_proj(const float* __restrict__ A,
    const float* __restrict__ Wt, const float* __restrict__ bias,
    float* __restrict__ out, int M) {
  __shared__ float As[64 * 257];
  const int t = threadIdx.x;
  const int l = t & 63;
  const int w = t >> 6;
  const int r0 = blockIdx.x * 64;

  // stage A tile: 64 rows x 256 cols (float4 loads, scalar LDS stores)
#pragma unroll
  for (int s = 0; s < 8; ++s) {
    int lin = t + s * 512;               // 0..4095
    int row = lin >> 6, kq = lin & 63;
    float4 v = make_float4(0.f, 0.f, 0.f, 0.f);
    if (r0 + row < M) v = ((const float4*)A)[(size_t)(r0 + row) * 64 + kq];
    float* d = &As[row * 257 + kq * 4];
    d[0] = v.x; d[1] = v.y; d[2] = v.z; d[3] = v.w;
  }
  __syncthreads();

  const int c0 = w * 32;
  const float* wbase = Wt + __builtin_amdgcn_readfirstlane(c0);
  f32x2 acc2[16];
#pragma unroll
  for (int c = 0; c < 16; ++c) acc2[c] = (f32x2){0.f, 0.f};

#pragma unroll 2
  for (int kk = 0; kk < 256; ++kk) {
    float a = As[l * 257 + kk];
    f32x2 a2 = {a, a};
    const float4* wp = (const float4*)(wbase + (kk << 8));
#pragma unroll
    for (int c4 = 0; c4 < 8; ++c4) {
      float4 wv = wp[c4];
      f32x2 lo = {wv.x, wv.y}, hi = {wv.z, wv.w};
      acc2[2 * c4]     = __builtin_elementwise_fma(a2, lo, acc2[2 * c4]);
      acc2[2 * c4 + 1] = __builtin_elementwise_fma(a2, hi, acc2[2 * c4 + 1]);
    }
  }
  __syncthreads();

  // transpose through LDS for coalesced stores
#pragma unroll
  for (int c = 0; c < 16; ++c) {
    As[l * 257 + c0 + 2 * c]     = acc2[c].x;
    As[l * 257 + c0 + 2 * c + 1] = acc2[c].y;
  }
  __syncthreads();
#pragma unroll
  for (int s = 0; s < 32; ++s) {
    int lin = t + s * 512;               // 0..16383
    int row = lin >> 8, col = lin & 255;
    if (r0 + row < M)
      out[(size_t)(r0 + row) * 256 + col] = As[row * 257 + col] + bias[col];
  }
}

// ---------------------------------------------------------------------------
// K2: RNN scan, one block per batch row b. 512 thr = 8 waves, ONE barrier
// per step. Wave w owns k-slice [32w,32w+32); lane l holds W_hh cols
// {l,l+64,l+128,l+192} over that slice (f32x2-packed, 4 indep FMA chains).
// KEY: wave w only ever needs h[32w..32w+32) for its broadcasts, and its
// own lanes compute exactly those columns in the epilogue (jv = 32w+(l&31),
// lanes 32-63 duplicate). So h stays IN REGISTERS across steps -- no h-LDS
// buffer, no second barrier. part[] is double-buffered so the single
// barrier also covers buffer reuse (a wave cannot be 2 iterations ahead).
// Epilogue partial-combine: part[buf][w'][jv], bank = jv%32, conflict-free
// (lanes 32-63 same-address broadcast).
// Writes per step t: hU[t*64+b] (reused by K3), ro[t+1] = h_{t+1};
// new_hidden into d_out[1..] at the last step. x0 is deferred to k_loss.
// ---------------------------------------------------------------------------
__global__ __launch_bounds__(512, 2) void k_scan(const float* __restrict__ proj,
    const int* __restrict__ data, const float* __restrict__ W_hh,
    const float* __restrict__ b_hh, const float* __restrict__ hidden,
    float* __restrict__ ro, float* __restrict__ hU, float* __restrict__ out) {
  __shared__ float part[2][8][256];
  __shared__ int   ldata[128];
  const int t = threadIdx.x, b = blockIdx.x;
  const int l = t & 63, w = t >> 6, w32 = w * 32;
  const int jv = w32 + (l & 31);        // epilogue column this lane owns

  // per-lane W slices, packed as col-pairs sharing the same k:
  // w01[i] = {W[l][w32+i], W[l+64][w32+i]}, w23[i] = {W[l+128][..], W[l+192][..]}
  f32x2 w01[32], w23[32];
  {
    const float4* r0 = (const float4*)(W_hh + (size_t)(l)*256 + w32);
    const float4* r1 = (const float4*)(W_hh + (size_t)(l + 64) * 256 + w32);
    const float4* r2 = (const float4*)(W_hh + (size_t)(l + 128) * 256 + w32);
    const float4* r3 = (const float4*)(W_hh + (size_t)(l + 192) * 256 + w32);
#pragma unroll
    for (int i4 = 0; i4 < 8; ++i4) {
      float4 v0 = r0[i4], v1 = r1[i4], v2 = r2[i4], v3 = r3[i4];
      w01[4 * i4 + 0] = (f32x2){v0.x, v1.x}; w01[4 * i4 + 1] = (f32x2){v0.y, v1.y};
      w01[4 * i4 + 2] = (f32x2){v0.z, v1.z}; w01[4 * i4 + 3] = (f32x2){v0.w, v1.w};
      w23[4 * i4 + 0] = (f32x2){v2.x, v3.x}; w23[4 * i4 + 1] = (f32x2){v2.y, v3.y};
      w23[4 * i4 + 2] = (f32x2){v2.z, v3.z}; w23[4 * i4 + 3] = (f32x2){v2.w, v3.w};
    }
  }
  if (t < 128) ldata[t] = data[t * 64 + b];
  __syncthreads();                       // ldata ready

  float hv = hidden[b * 256 + jv];       // register-resident h (2-way dup)
  if (l < 32) ro[b * 256 + jv] = hv;     // ro[0] = hidden
  const float bhh = b_hh[jv];
  float xv = proj[(size_t)ldata[0] * 256 + jv];

  for (int st = 0; st < 128; ++st) {
    const int buf = st & 1;
    // dot: this wave's k-slice partial for cols (l, l+64, l+128, l+192);
    // h broadcasts come straight from lane registers (lanes 0-31 hold
    // h[w32..w32+32) computed by last step's epilogue).
    f32x2 a01a = {0.f, 0.f}, a01b = {0.f, 0.f};
    f32x2 a23a = {0.f, 0.f}, a23b = {0.f, 0.f};
#pragma unroll
    for (int i = 0; i < 32; i += 2) {
      float h0 = rlf(hv, i), h1 = rlf(hv, i + 1);
      f32x2 h0p = {h0, h0}, h1p = {h1, h1};
      a01a = __builtin_elementwise_fma(h0p, w01[i],     a01a);
      a23a = __builtin_elementwise_fma(h0p, w23[i],     a23a);
      a01b = __builtin_elementwise_fma(h1p, w01[i + 1], a01b);
      a23b = __builtin_elementwise_fma(h1p, w23[i + 1], a23b);
    }
    f32x2 a01 = a01a + a01b, a23 = a23a + a23b;
    part[buf][w][l]       = a01.x;
    part[buf][w][l + 64]  = a01.y;
    part[buf][w][l + 128] = a23.x;
    part[buf][w][l + 192] = a23.y;

    // prefetch next step's x for this lane's own column (hidden by barrier)
    float xvn = 0.f;
    if (st < 127) xvn = proj[(size_t)ldata[st + 1] * 256 + jv];

    __syncthreads();

    // every wave reduces its OWN h-slice columns; h never leaves registers
    float hu = ((part[buf][0][jv] + part[buf][1][jv])
              + (part[buf][2][jv] + part[buf][3][jv]))
             + ((part[buf][4][jv] + part[buf][5][jv])
              + (part[buf][6][jv] + part[buf][7][jv])) + bhh;
    float hn = tanh_fast(hu + xv);
    hv = hn;
    const int p = st * 64 + b;
    if (l < 32) {
      hU[(size_t)p * 256 + jv] = hu;
      ro[((size_t)p + 64) * 256 + jv] = hn;
      if (st == 127) out[1 + b * 256 + jv] = hn;   // new_hidden
    }
    xv = xvn;
  }
}

// ---------------------------------------------------------------------------
// K3: positives + negatives + per-column logsumexp. One wave per column p
// (4 waves/block). Lane q-strided j = l + 64q. Computes x0 itself from
// ro[p], ro[p+64], bias_vec[data[p]]. Negatives processed 4 PER ITERATION:
// the four 6-step shuffle-reduce chains are independent and interleave on
// the SIMD. Depth-4 prefetch of the next 4 proj rows. Partial -> lossP.
// ---------------------------------------------------------------------------
__global__ __launch_bounds__(256, 4) void k_loss(const float* __restrict__ ro,
    const float* __restrict__ hU, const float* __restrict__ proj,
    const int* __restrict__ samples, const float* __restrict__ bias_vec,
    const int* __restrict__ data, float* __restrict__ lossP) {
  const int t = threadIdx.x, l = t & 63, w = t >> 6;
  const int p = blockIdx.x * 4 + w;
  float hp[4], hu[4];
  float x0v;
  {
    float dsq = 0.f;
#pragma unroll
    for (int q = 0; q < 4; ++q) {
      hp[q] = ro[(size_t)p * 256 + 64 * q + l];
      hu[q] = hU[(size_t)p * 256 + 64 * q + l];
      float hn = ro[((size_t)p + 64) * 256 + 64 * q + l];
      float d = hp[q] - hn;
      dsq = fmaf(d, d, dsq);
    }
#pragma unroll
    for (int m = 1; m < 64; m <<= 1) dsq += __shfl_xor(dsq, m);
    x0v = TEMPC * (bias_vec[data[p]] - dsq);   // positive logit
  }
  int   stok  = (l < 32) ? samples[(size_t)l * SB + p] : 0;
  float sbias = (l < 32) ? bias_vec[stok] : 0.f;

  // prime: rows for negatives 0..3
  float cr[4][4];
#pragma unroll
  for (int m = 0; m < 4; ++m) {
    int tk = __builtin_amdgcn_readlane(stok, m);
    const float* pr = proj + (size_t)tk * 256;
#pragma unroll
    for (int q = 0; q < 4; ++q) cr[m][q] = pr[64 * q + l];
  }

  float lg = 0.f;                         // lane n (<32) will hold logit n
  for (int n0 = 0; n0 < 32; n0 += 4) {
    float nx[4][4];
    if (n0 < 28) {                        // issue next 4 rows' loads first
#pragma unroll
      for (int m = 0; m < 4; ++m) {
        int tk = __builtin_amdgcn_readlane(stok, n0 + 4 + m);
        const float* pr = proj + (size_t)tk * 256;
#pragma unroll
        for (int q = 0; q < 4; ++q) nx[m][q] = pr[64 * q + l];
      }
    }
    float s[4];
#pragma unroll
    for (int m = 0; m < 4; ++m) {
      float acc = 0.f;
#pragma unroll
      for (int q = 0; q < 4; ++q) {
        float o = tanh_fast(cr[m][q] + hu[q]);
        float d = hp[q] - o;
        acc = fmaf(d, d, acc);
      }
      s[m] = acc;
    }
    // 4 independent butterfly reduces, interleaved
#pragma unroll
    for (int sh = 1; sh < 64; sh <<= 1) {
#pragma unroll
      for (int m = 0; m < 4; ++m) s[m] += __shfl_xor(s[m], sh);
    }
#pragma unroll
    for (int m = 0; m < 4; ++m) {
      float bn = rlf(sbias, n0 + m);
      float logit = TEMPC * (bn - s[m]);
      if (l == n0 + m) lg = logit;
    }
    if (n0 < 28) {
#pragma unroll
      for (int m = 0; m < 4; ++m)
#pragma unroll
        for (int q = 0; q < 4; ++q) cr[m][q] = nx[m][q];
    }
  }

  float v = (l < 32) ? lg : ((l == 32) ? x0v : -INFINITY);
  float mx = v;
#pragma unroll
  for (int m = 1; m < 64; m <<= 1) mx = fmaxf(mx, __shfl_xor(mx, m));
  float e = (l < 33) ? __expf(v - mx) : 0.f;
#pragma unroll
  for (int m = 1; m < 64; m <<= 1) e += __shfl_xor(e, m);
  float lse = mx + __logf(e);

  __shared__ float bl[4];
  if (l == 0) bl[w] = lse - x0v;
  __syncthreads();
  if (t == 0) lossP[blockIdx.x] = (bl[0] + bl[1] + bl[2] + bl[3]);
}

// ---------------------------------------------------------------------------
// K4: out[0] = sum(lossP)/8192 + BIAS_REG * sum(bias_vec^2). One block,
// 1024 thr = 16 waves; no atomics anywhere.
// ---------------------------------------------------------------------------
__global__ __launch_bounds__(1024) void k_final(const float* __restrict__ lossP,
    const float* __restrict__ bv, float* __restrict__ out) {
  const int t = threadIdx.x, l = t & 63, w = t >> 6;
  float sa = 0.f;
  for (int i = t; i < 2048; i += 1024) sa += lossP[i];
  float sb = 0.f;
  for (int i = t; i < 12500; i += 1024) {     // 50000 = 12500 float4 exactly
    float4 v = ((const float4*)bv)[i];
    sb += v.x * v.x + v.y * v.y + v.z * v.z + v.w * v.w;
  }
#pragma unroll
  for (int m = 1; m < 64; m <<= 1) {
    sa += __shfl_xor(sa, m);
    sb += __shfl_xor(sb, m);
  }
  __shared__ float wa[16], wb[16];
  if (l == 0) { wa[w] = sa; wb[w] = sb; }
  __syncthreads();
  if (t == 0) {
    float ta = 0.f, tb = 0.f;
#pragma unroll
    for (int i = 0; i < 16; ++i) { ta += wa[i]; tb += wb[i]; }
    out[0] = ta * (1.0f / 8192.0f) + tb;
  }
}

// ---------------------------------------------------------------------------
extern "C" void kernel_launch(void* const* d_in, const int* in_sizes, int n_in,
                              void* d_out, int out_size, void* d_ws, size_t ws_size,
                              hipStream_t stream) {
  const int*   data     = (const int*)  d_in[0];
  const float* hidden   = (const float*)d_in[1];
  const int*   samples  = (const int*)  d_in[2];
  const float* emb      = (const float*)d_in[3];
  const float* W_ih     = (const float*)d_in[4];
  const float* b_ih     = (const float*)d_in[5];
  const float* W_hh     = (const float*)d_in[6];
  const float* b_hh     = (const float*)d_in[7];
  const float* bias_vec = (const float*)d_in[8];
  float* out = (float*)d_out;
  float* ws  = (float*)d_ws;

  // workspace layout (floats): total ~17.08M floats = 68.3 MB
  float* proj  = ws;                      // 50000*256 = 12,800,000
  float* Wt    = proj + 12800000;         // 256*256   = 65,536
  float* ro    = Wt + 65536;              // 129*64*256 = 2,113,536
  float* hU    = ro + 2113536;            // 8192*256  = 2,097,152
  float* lossP = hU + 2097152;            // 2,048

  k_prep <<<256, 256, 0, stream>>>(W_ih, Wt);
  k_proj <<<782, 512, 0, stream>>>(emb, Wt, b_ih, proj, NT);
  k_scan <<<64, 512, 0, stream>>>(proj, data, W_hh, b_hh, hidden, ro, hU, out);
  k_loss <<<2048, 256, 0, stream>>>(ro, hU, proj, samples, bias_vec, data, lossP);
  k_final<<<1, 1024, 0, stream>>>(lossP, bias_vec, out);
}